// Round 13
// baseline (106.565 us; speedup 1.0000x reference)
//
#include <hip/hip_runtime.h>
#include <hip/hip_bf16.h>
#include <stdint.h>

typedef __bf16 bf16;
typedef __bf16 bf16x8 __attribute__((ext_vector_type(8)));
typedef __bf16 bf16x4 __attribute__((ext_vector_type(4)));
typedef float f32x4 __attribute__((ext_vector_type(4)));

#define KDIM 768
#define NHEAD 12
#define HDIM 64
#define NTOK 1024
#define BATCH 8

// XOR swizzle for row-major [row][128B-row] LDS tiles (attention)
#define SWZ(row, b) ((b) ^ (((row) & 7) << 4))

__device__ __forceinline__ void gl_lds16(const bf16* g, bf16* l) {
    __builtin_amdgcn_global_load_lds((const __attribute__((address_space(1))) void*)g,
                                     (__attribute__((address_space(3))) void*)l, 16, 0, 0);
}
__device__ __forceinline__ void gl_lds16f(const float* g, float* l) {
    __builtin_amdgcn_global_load_lds((const __attribute__((address_space(1))) void*)g,
                                     (__attribute__((address_space(3))) void*)l, 16, 0, 0);
}

#define G_MFMA(a, b, c) __builtin_amdgcn_mfma_f32_16x16x32_bf16(a, b, c, 0, 0, 0)
#define VMW(N) asm volatile("s_waitcnt vmcnt(" #N ")" ::: "memory")

// ---------------- fp32 -> bf16 convert (weights only; x stays f32, fused into qkv) --
__global__ void k_cvt_w(const float* __restrict__ wq, const float* __restrict__ wp,
                        bf16* __restrict__ wqb, bf16* __restrict__ wpb) {
    int b = blockIdx.x;
    const float* src;
    bf16* dst;
    int base;
    if (b < 1728) { src = wq; dst = wqb; base = b; }
    else          { src = wp; dst = wpb; base = b - 1728; }
    int i = (base * 256 + threadIdx.x) * 4;
    float4 v = *(const float4*)(src + i);
    bf16x4 o;
    o[0] = (bf16)v.x; o[1] = (bf16)v.y; o[2] = (bf16)v.z; o[3] = (bf16)v.w;
    *(bf16x4*)(dst + i) = o;
}

// =====================================================================================
// QKV GEMM with fused x-conversion: r9 fine-phase schedule UNCHANGED; only the A tile
// is f32 (staged straight from global x via global_load_lds — no separate cvt pass).
// 128(M) x 192(N) x K, BK=32, 4 waves (2x2), per-wave 64x96 (acc[4][6]).
// LDS: A 2x16KB f32 + B 2x12KB bf16 = 56KB (2 blocks/CU, same as r12 achieved).
// A-frag: 2x ds_read_b128 f32 + 8 casts (hidden under the 12-MFMA cluster).
// A swizzle (128B rows): chunk p stores global chunk p^(row&7); pre-swizzled source
// (thread t -> row t>>3 (+32q), src chunk (t&7)^((t>>3)&7)); frag reads 2-way (free).
// Counted vmcnt(3)/tile: in-flight = B(kt+1)x3 + A(kt+1)x4 + B(kt+2)x3 -> drain 7.
// =====================================================================================

#define AFRAG(dst, A8, row) do {                                                \
    const int rb_ = (row) * 128;                                                \
    float4 w0_ = *(const float4*)((A8) + rb_ + a0off);                          \
    float4 w1_ = *(const float4*)((A8) + rb_ + a1off);                          \
    dst[0] = (bf16)w0_.x; dst[1] = (bf16)w0_.y;                                 \
    dst[2] = (bf16)w0_.z; dst[3] = (bf16)w0_.w;                                 \
    dst[4] = (bf16)w1_.x; dst[5] = (bf16)w1_.y;                                 \
    dst[6] = (bf16)w1_.z; dst[7] = (bf16)w1_.w;                                 \
} while (0)

#define QTILEF(S, kA, kB, doA, doB, vmn) do {                                   \
    const char* A8 = (const char*)sAf[S];                                       \
    const char* B8 = (const char*)sB[S];                                        \
    bf16x8 af[2], bfr[6];                                                       \
    AFRAG(af[0], A8, wr * 64 + 0 + lr);                                         \
    AFRAG(af[1], A8, wr * 64 + 16 + lr);                                        \
    _Pragma("unroll")                                                           \
    for (int n = 0; n < 6; ++n)                                                 \
        bfr[n] = *(const bf16x8*)(B8 + (wc * 96 + n * 16 + lr) * 64 + kxoff);   \
    if (doA) {                                                                  \
        const float* p_ = XAst + (size_t)(kA) * 32;                             \
        float* d_ = &sAf[(S) ^ 1][t * 4];                                       \
        gl_lds16f(p_,                       d_);                                \
        gl_lds16f(p_ + (size_t)32 * KDIM,   d_ + 1024);                         \
        gl_lds16f(p_ + (size_t)64 * KDIM,   d_ + 2048);                         \
        gl_lds16f(p_ + (size_t)96 * KDIM,   d_ + 3072);                         \
    }                                                                           \
    __builtin_amdgcn_s_setprio(1);                                              \
    _Pragma("unroll")                                                           \
    for (int m = 0; m < 2; ++m)                                                 \
        _Pragma("unroll")                                                       \
        for (int n = 0; n < 6; ++n)                                             \
            acc[m][n] = G_MFMA(af[m], bfr[n], acc[m][n]);                       \
    __builtin_amdgcn_s_setprio(0);                                              \
    __builtin_amdgcn_s_barrier();                                               \
    AFRAG(af[0], A8, wr * 64 + 32 + lr);                                        \
    AFRAG(af[1], A8, wr * 64 + 48 + lr);                                        \
    if (doB) {                                                                  \
        const bf16* p_ = Wst + (size_t)(kB) * 32;                               \
        gl_lds16(p_,                     &sB[S][t * 8]);                        \
        gl_lds16(p_ + (size_t)64 * KDIM,  &sB[S][t * 8 + 2048]);                \
        gl_lds16(p_ + (size_t)128 * KDIM, &sB[S][t * 8 + 4096]);                \
    }                                                                           \
    __builtin_amdgcn_s_setprio(1);                                              \
    _Pragma("unroll")                                                           \
    for (int m = 0; m < 2; ++m)                                                 \
        _Pragma("unroll")                                                       \
        for (int n = 0; n < 6; ++n)                                             \
            acc[m + 2][n] = G_MFMA(af[m], bfr[n], acc[m + 2][n]);               \
    __builtin_amdgcn_s_setprio(0);                                              \
    if ((vmn) == 3) { VMW(3); } else if ((vmn) == 0) { VMW(0); }                \
    __builtin_amdgcn_s_barrier();                                               \
} while (0)

__global__ __launch_bounds__(256, 2) void k_gemm_qkv(
    const float* __restrict__ X, const bf16* __restrict__ W,
    bf16* __restrict__ qb, bf16* __restrict__ kb, bf16* __restrict__ vb)
{
    __shared__ __attribute__((aligned(16))) float sAf[2][4096];  // 128 rows x 32 f32
    __shared__ __attribute__((aligned(16))) bf16 sB[2][6144];    // 192 rows x 32 bf16
    const int t = threadIdx.x;
    const int lane = t & 63;
    const int wv = t >> 6;
    const int wr = wv >> 1, wc = wv & 1;
    const int lr = lane & 15, lg = lane >> 4;
    const int kxoff = (lg << 4) ^ (((lr >> 1) & 3) << 4);        // B frag (64B rows)
    const int xorb4 = (lr & 7) << 4;                             // A frag (128B rows)
    const int a0off = (lg << 5) ^ xorb4;
    const int a1off = ((lg << 5) | 16) ^ xorb4;
    const int srow = t >> 2;
    const int spos = ((t & 3) ^ ((t >> 3) & 3)) * 8;             // B pre-swizzled src
    const int bm = blockIdx.x, bn = blockIdx.y;
    const float* XAst = X + (size_t)(bm * 128 + (t >> 3)) * KDIM
                          + (size_t)(((t & 7) ^ ((t >> 3) & 7)) * 4);
    const bf16* Wb = W + (size_t)bn * 192 * KDIM;
    const bf16* Wst = Wb + (size_t)srow * KDIM + spos;
    f32x4 acc[4][6] = {};

    // prologue: A(0) x4, B(0) x3, B(1) x3; drain to 3 (A0,B0 ready)
    {
        float* d_ = &sAf[0][t * 4];
        gl_lds16f(XAst,                       d_);
        gl_lds16f(XAst + (size_t)32 * KDIM,   d_ + 1024);
        gl_lds16f(XAst + (size_t)64 * KDIM,   d_ + 2048);
        gl_lds16f(XAst + (size_t)96 * KDIM,   d_ + 3072);
    }
    gl_lds16(Wst,                      &sB[0][t * 8]);
    gl_lds16(Wst + (size_t)64 * KDIM,  &sB[0][t * 8 + 2048]);
    gl_lds16(Wst + (size_t)128 * KDIM, &sB[0][t * 8 + 4096]);
    gl_lds16(Wst + 32,                      &sB[1][t * 8]);
    gl_lds16(Wst + 32 + (size_t)64 * KDIM,  &sB[1][t * 8 + 2048]);
    gl_lds16(Wst + 32 + (size_t)128 * KDIM, &sB[1][t * 8 + 4096]);
    VMW(3);
    __builtin_amdgcn_s_barrier();

#pragma unroll 1
    for (int g = 0; g < 11; ++g) {
        QTILEF(0, 2 * g + 1, 2 * g + 2, 1, 1, 3);   // kt = 2g
        QTILEF(1, 2 * g + 2, 2 * g + 3, 1, 1, 3);   // kt = 2g+1
    }
    QTILEF(0, 23, 0, 1, 0, 0);   // kt = 22: stage A(23), vmcnt(0)
    QTILEF(1, 0, 0, 0, 0, -1);   // kt = 23: compute only

    const float QSC = 0.18033688011112042f;  // 0.125 * log2(e) folded into q
#pragma unroll
    for (int n = 0; n < 6; ++n) {
        int o = bn * 192 + wc * 96 + n * 16 + lr;
        int s = o / 768;
        int rem = o - s * 768;
        int head = rem >> 6;
        int d = o & 63;
        bf16* dst = (s == 0) ? qb : ((s == 1) ? kb : vb);
        float sc = (s == 0) ? QSC : 1.0f;
#pragma unroll
        for (int m = 0; m < 4; ++m) {
            int grow = bm * 128 + wr * 64 + m * 16 + lg * 4;
            int bidx = grow >> 10;
            int tok = grow & 1023;
            size_t base = (((size_t)bidx * NHEAD + head) * NTOK + tok) * HDIM + d;
#pragma unroll
            for (int r = 0; r < 4; ++r)
                dst[base + (size_t)r * HDIM] = (bf16)(acc[m][n][r] * sc);
        }
    }
}

// =====================================================================================
// Proj GEMM: r12-exact fine-phase bf16 path (verified ~14us)
// =====================================================================================
#define QTILE(S, kA, kB, doA, doB, vmn) do {                                    \
    const char* A8 = (const char*)sA[S];                                        \
    const char* B8 = (const char*)sB[S];                                        \
    bf16x8 af[2], bfr[6];                                                       \
    af[0] = *(const bf16x8*)(A8 + (wr * 64 + 0 + lr) * 64 + kxoff);             \
    af[1] = *(const bf16x8*)(A8 + (wr * 64 + 16 + lr) * 64 + kxoff);            \
    _Pragma("unroll")                                                           \
    for (int n = 0; n < 6; ++n)                                                 \
        bfr[n] = *(const bf16x8*)(B8 + (wc * 96 + n * 16 + lr) * 64 + kxoff);   \
    if (doA) {                                                                  \
        const bf16* p_ = Ast + (size_t)(kA) * 32;                               \
        gl_lds16(p_,                    &sA[(S) ^ 1][t * 8]);                   \
        gl_lds16(p_ + (size_t)64 * KDIM, &sA[(S) ^ 1][t * 8 + 2048]);           \
    }                                                                           \
    __builtin_amdgcn_s_setprio(1);                                              \
    _Pragma("unroll")                                                           \
    for (int m = 0; m < 2; ++m)                                                 \
        _Pragma("unroll")                                                       \
        for (int n = 0; n < 6; ++n)                                             \
            acc[m][n] = G_MFMA(af[m], bfr[n], acc[m][n]);                       \
    __builtin_amdgcn_s_setprio(0);                                              \
    __builtin_amdgcn_s_barrier();                                               \
    af[0] = *(const bf16x8*)(A8 + (wr * 64 + 32 + lr) * 64 + kxoff);            \
    af[1] = *(const bf16x8*)(A8 + (wr * 64 + 48 + lr) * 64 + kxoff);            \
    if (doB) {                                                                  \
        const bf16* p_ = Wst + (size_t)(kB) * 32;                               \
        gl_lds16(p_,                     &sB[S][t * 8]);                        \
        gl_lds16(p_ + (size_t)64 * KDIM,  &sB[S][t * 8 + 2048]);                \
        gl_lds16(p_ + (size_t)128 * KDIM, &sB[S][t * 8 + 4096]);                \
    }                                                                           \
    __builtin_amdgcn_s_setprio(1);                                              \
    _Pragma("unroll")                                                           \
    for (int m = 0; m < 2; ++m)                                                 \
        _Pragma("unroll")                                                       \
        for (int n = 0; n < 6; ++n)                                             \
            acc[m + 2][n] = G_MFMA(af[m], bfr[n], acc[m + 2][n]);               \
    __builtin_amdgcn_s_setprio(0);                                              \
    if ((vmn) == 3) { VMW(3); } else if ((vmn) == 0) { VMW(0); }                \
    __builtin_amdgcn_s_barrier();                                               \
} while (0)

__global__ __launch_bounds__(256, 3) void k_gemm_proj(
    const bf16* __restrict__ A, const bf16* __restrict__ W,
    const float* __restrict__ bias, float* __restrict__ out)
{
    __shared__ __attribute__((aligned(16))) bf16 sA[2][4096];
    __shared__ __attribute__((aligned(16))) bf16 sB[2][6144];
    const int t = threadIdx.x;
    const int lane = t & 63;
    const int wv = t >> 6;
    const int wr = wv >> 1, wc = wv & 1;
    const int lr = lane & 15, lg = lane >> 4;
    const int kxoff = (lg << 4) ^ (((lr >> 1) & 3) << 4);
    const int srow = t >> 2;
    const int spos = ((t & 3) ^ ((t >> 3) & 3)) * 8;
    const int bm = blockIdx.x, bn = blockIdx.y;
    const bf16* Ab = A + (size_t)bm * 128 * KDIM;
    const bf16* Wb = W + (size_t)bn * 192 * KDIM;
    const bf16* Ast = Ab + (size_t)srow * KDIM + spos;
    const bf16* Wst = Wb + (size_t)srow * KDIM + spos;
    f32x4 acc[4][6] = {};
    gl_lds16(Ast,                     &sA[0][t * 8]);
    gl_lds16(Ast + (size_t)64 * KDIM, &sA[0][t * 8 + 2048]);
    gl_lds16(Wst,                      &sB[0][t * 8]);
    gl_lds16(Wst + (size_t)64 * KDIM,  &sB[0][t * 8 + 2048]);
    gl_lds16(Wst + (size_t)128 * KDIM, &sB[0][t * 8 + 4096]);
    gl_lds16(Wst + 32,                      &sB[1][t * 8]);
    gl_lds16(Wst + 32 + (size_t)64 * KDIM,  &sB[1][t * 8 + 2048]);
    gl_lds16(Wst + 32 + (size_t)128 * KDIM, &sB[1][t * 8 + 4096]);
    VMW(3);
    __builtin_amdgcn_s_barrier();
#pragma unroll 1
    for (int g = 0; g < 11; ++g) {
        QTILE(0, 2 * g + 1, 2 * g + 2, 1, 1, 3);
        QTILE(1, 2 * g + 2, 2 * g + 3, 1, 1, 3);
    }
    QTILE(0, 23, 0, 1, 0, 0);
    QTILE(1, 0, 0, 0, 0, -1);

#pragma unroll
    for (int n = 0; n < 6; ++n) {
        int col = bn * 192 + wc * 96 + n * 16 + lr;
        float bv = bias[col];
#pragma unroll
        for (int m = 0; m < 4; ++m) {
            int grow = bm * 128 + wr * 64 + m * 16 + lg * 4;
#pragma unroll
            for (int r = 0; r < 4; ++r)
                out[(size_t)(grow + r) * KDIM + col] = acc[m][n][r] + bv;
        }
    }
}

// =====================================================================================
// Banded flash attention (r12-exact: 64-key steps, static-max softmax)
// =====================================================================================
__global__ __launch_bounds__(256) void k_attn(
    const bf16* __restrict__ qbuf, const bf16* __restrict__ kbuf,
    const bf16* __restrict__ vbuf, bf16* __restrict__ ob)
{
    const int x = blockIdx.x;
    const int sub = x >> 3;
    const int bh = (x & 7) * 12 + (sub >> 4);   // 12 bh per XCD
    const int qblk = sub & 15;                   // == h_q
    const int head = bh % NHEAD, bidx = bh / NHEAD;
    const bf16* Q  = qbuf + (size_t)bh * NTOK * HDIM;
    const bf16* Kp = kbuf + (size_t)bh * NTOK * HDIM;
    const bf16* Vp = vbuf + (size_t)bh * NTOK * HDIM;

    const int t = threadIdx.x, lane = t & 63, wv = t >> 6;
    const int lr = lane & 15, lg = lane >> 4, lkb = lg * 8;

    __shared__ bf16 Ks[2][64 * 64];   // [key][d], swizzled
    __shared__ bf16 vT[2][64 * 64];   // [d][key], swizzled
    __shared__ bf16 pls[4][16 * 64];  // per-wave P [q][key], swizzled

    {
        bf16x8 z = {};
        *(bf16x8*)&pls[wv][lane * 16] = z;
        *(bf16x8*)&pls[wv][lane * 16 + 8] = z;
    }

    bf16x8 qf[2];
#pragma unroll
    for (int ks = 0; ks < 2; ++ks)
        qf[ks] = *(const bf16x8*)(Q + (size_t)(qblk * 64 + wv * 16 + lr) * HDIM + ks * 32 + lkb);

    f32x4 acc[4] = {};
    float lrow[4] = {0.f, 0.f, 0.f, 0.f};

    const int kh0 = (qblk - 3 < 0) ? 0 : qblk - 3;
    const int kh1 = (qblk + 3 > 15) ? 15 : qblk + 3;

    const int sj = t >> 2;
    const int sd = (t & 3) * 16;

    const bf16* ks0 = Kp + (size_t)(kh0 * 64 + sj) * HDIM + sd;
    const bf16* vs0 = Vp + (size_t)(kh0 * 64 + sj) * HDIM + sd;
    bf16x8 gk0 = *(const bf16x8*)ks0, gk1 = *(const bf16x8*)(ks0 + 8);
    bf16x8 gv0 = *(const bf16x8*)vs0, gv1 = *(const bf16x8*)(vs0 + 8);

    char* pb8 = (char*)pls[wv];
    const int wq0 = wv * 16 + lg * 4;
    int cur = 0;

    for (int kh = kh0; kh <= kh1; ++kh) {
        char* kb8 = (char*)Ks[cur];
        char* vb8 = (char*)vT[cur];
        {
            int kbo = sj * 128 + sd * 2;
            *(bf16x8*)(kb8 + SWZ(sj, kbo)) = gk0;
            *(bf16x8*)(kb8 + SWZ(sj, kbo + 16)) = gk1;
        }
#pragma unroll
        for (int ii = 0; ii < 8; ++ii) {
            int d = sd + ii;
            *(bf16*)(vb8 + SWZ(d, (d << 7) + (sj << 1))) = gv0[ii];
        }
#pragma unroll
        for (int ii = 0; ii < 8; ++ii) {
            int d = sd + 8 + ii;
            *(bf16*)(vb8 + SWZ(d, (d << 7) + (sj << 1))) = gv1[ii];
        }
        if (kh < kh1) {
            const bf16* kn = Kp + (size_t)((kh + 1) * 64 + sj) * HDIM + sd;
            const bf16* vn = Vp + (size_t)((kh + 1) * 64 + sj) * HDIM + sd;
            gk0 = *(const bf16x8*)kn; gk1 = *(const bf16x8*)(kn + 8);
            gv0 = *(const bf16x8*)vn; gv1 = *(const bf16x8*)(vn + 8);
        }
        asm volatile("s_waitcnt lgkmcnt(0)" ::: "memory");
        __builtin_amdgcn_s_barrier();

        // ---- QK^T + P = exp2(s) (static max; banded logits are bounded) ----
        float psum[4] = {0.f, 0.f, 0.f, 0.f};
#pragma unroll
        for (int jj = 0; jj < 3; ++jj) {
            int j = wv - 1 + jj;
            if (j >= 0 && j <= 3) {        // wave-uniform
                int key = j * 16 + lr;
                int kbase = key * 128;
                bf16x8 kf0 = *(const bf16x8*)(kb8 + SWZ(key, kbase + lg * 16));
                bf16x8 kf1 = *(const bf16x8*)(kb8 + SWZ(key, kbase + 64 + lg * 16));
                f32x4 sv = {};
                sv = G_MFMA(qf[0], kf0, sv);
                sv = G_MFMA(qf[1], kf1, sv);
#pragma unroll
                for (int r = 0; r < 4; ++r) {
                    int dw = wq0 + r - key;
                    float p = (dw >= -5 && dw <= 5) ? exp2f(sv[r]) : 0.0f;
                    psum[r] += p;
                    int row = lg * 4 + r;
                    *(bf16*)(pb8 + SWZ(row, row * 128 + key * 2)) = (bf16)p;
                }
            }
        }
#pragma unroll
        for (int r = 0; r < 4; ++r) lrow[r] += psum[r];

        // ---- PV: A = P[16x64], B = V^T ----
        bf16x8 pf0 = *(const bf16x8*)(pb8 + SWZ(lr, lr * 128 + lg * 16));
        bf16x8 pf1 = *(const bf16x8*)(pb8 + SWZ(lr, lr * 128 + 64 + lg * 16));
#pragma unroll
        for (int dt = 0; dt < 4; ++dt) {
            int vrow = dt * 16 + lr;
            bf16x8 vf0 = *(const bf16x8*)(vb8 + SWZ(vrow, vrow * 128 + lg * 16));
            bf16x8 vf1 = *(const bf16x8*)(vb8 + SWZ(vrow, vrow * 128 + 64 + lg * 16));
            acc[dt] = G_MFMA(pf0, vf0, acc[dt]);
            acc[dt] = G_MFMA(pf1, vf1, acc[dt]);
        }
        cur ^= 1;
    } // kh

    // ---- finalize ----
#pragma unroll
    for (int off = 1; off < 16; off <<= 1)
#pragma unroll
        for (int r = 0; r < 4; ++r) lrow[r] += __shfl_xor(lrow[r], off);

#pragma unroll
    for (int r = 0; r < 4; ++r) {
        float inv = 1.0f / lrow[r];
        int tok = qblk * 64 + wv * 16 + lg * 4 + r;
        size_t rowbase = ((size_t)bidx * NTOK + tok) * KDIM + head * HDIM;
#pragma unroll
        for (int dt = 0; dt < 4; ++dt)
            ob[rowbase + dt * 16 + lr] = (bf16)(acc[dt][r] * inv);
    }
}

// ---------------- launcher ----------------
extern "C" void kernel_launch(void* const* d_in, const int* in_sizes, int n_in,
                              void* d_out, int out_size, void* d_ws, size_t ws_size,
                              hipStream_t stream) {
    const float* x      = (const float*)d_in[0];
    const float* w_qkv  = (const float*)d_in[1];
    const float* w_proj = (const float*)d_in[2];
    const float* b_proj = (const float*)d_in[3];
    float* out = (float*)d_out;

    char* ws = (char*)d_ws;
    bf16* wqb = (bf16*)(ws);                  // 2304*768*2   =  3538944
    bf16* wpb = (bf16*)(ws + 3538944);        // 768*768*2    =  1179648
    bf16* qb  = (bf16*)(ws + 4718592);        // 96*1024*64*2 = 12582912
    bf16* kb  = (bf16*)(ws + 17301504);
    bf16* vb  = (bf16*)(ws + 29884416);
    bf16* aob = (bf16*)(ws + 42467328);       // attn out bf16 [8192][768]

    hipLaunchKernelGGL(k_cvt_w,    dim3(2304), dim3(256), 0, stream, w_qkv, w_proj, wqb, wpb);
    hipLaunchKernelGGL(k_gemm_qkv, dim3(64, 12), dim3(256), 0, stream, x, wqb, qb, kb, vb);
    hipLaunchKernelGGL(k_attn,     dim3(1536), dim3(256), 0, stream, qb, kb, vb, aob);
    hipLaunchKernelGGL(k_gemm_proj, dim3(64, 4), dim3(256), 0, stream, aob, wpb, b_proj, out);
}

// Round 14
// 101.092 us; speedup vs baseline: 1.0541x; 1.0541x over previous
//
#include <hip/hip_runtime.h>
#include <hip/hip_bf16.h>
#include <stdint.h>

typedef __bf16 bf16;
typedef __bf16 bf16x8 __attribute__((ext_vector_type(8)));
typedef __bf16 bf16x4 __attribute__((ext_vector_type(4)));
typedef float f32x4 __attribute__((ext_vector_type(4)));

#define KDIM 768
#define NHEAD 12
#define HDIM 64
#define NTOK 1024
#define BATCH 8

// XOR swizzle for row-major [row][128B-row] LDS tiles (attention)
#define SWZ(row, b) ((b) ^ (((row) & 7) << 4))

__device__ __forceinline__ void gl_lds16(const bf16* g, bf16* l) {
    __builtin_amdgcn_global_load_lds((const __attribute__((address_space(1))) void*)g,
                                     (__attribute__((address_space(3))) void*)l, 16, 0, 0);
}

#define G_MFMA(a, b, c) __builtin_amdgcn_mfma_f32_16x16x32_bf16(a, b, c, 0, 0, 0)
#define VMW(N) asm volatile("s_waitcnt vmcnt(" #N ")" ::: "memory")

// ---------------- fp32 -> bf16 convert (all three tensors, one launch) ----------------
__global__ void k_cvt_all(const float* __restrict__ x, const float* __restrict__ wq,
                          const float* __restrict__ wp, bf16* __restrict__ xb,
                          bf16* __restrict__ wqb, bf16* __restrict__ wpb) {
    int b = blockIdx.x;
    const float* src;
    bf16* dst;
    int base;
    if (b < 6144)       { src = x;  dst = xb;  base = b; }
    else if (b < 7872)  { src = wq; dst = wqb; base = b - 6144; }
    else                { src = wp; dst = wpb; base = b - 7872; }
    int i = (base * 256 + threadIdx.x) * 4;
    float4 v = *(const float4*)(src + i);
    bf16x4 o;
    o[0] = (bf16)v.x; o[1] = (bf16)v.y; o[2] = (bf16)v.z; o[3] = (bf16)v.w;
    *(bf16x4*)(dst + i) = o;
}

// =====================================================================================
// Fine-phase GEMM (r9 structure, verified 43us): 128(M) x 192(N) x K, BK=32,
// 4 waves (2x2), per-wave 64x96 (acc[4][6]). 2-slot LDS (40KB). Region-split
// retirement: B[s] retired after ph0 (frags reg-held), A[s] half per phase.
// Stage A(kt+1)->sA[s^1] in ph0, B(kt+2)->sB[s] in ph1. Counted vmcnt(3)/tile,
// 2 barriers/tile, setprio on MFMA clusters, zero-conflict XOR swizzle.
// =====================================================================================
#define QTILE(S, kA, kB, doA, doB, vmn) do {                                    \
    const char* A8 = (const char*)sA[S];                                        \
    const char* B8 = (const char*)sB[S];                                        \
    bf16x8 af[2], bfr[6];                                                       \
    af[0] = *(const bf16x8*)(A8 + (wr * 64 + 0 + lr) * 64 + kxoff);             \
    af[1] = *(const bf16x8*)(A8 + (wr * 64 + 16 + lr) * 64 + kxoff);            \
    _Pragma("unroll")                                                           \
    for (int n = 0; n < 6; ++n)                                                 \
        bfr[n] = *(const bf16x8*)(B8 + (wc * 96 + n * 16 + lr) * 64 + kxoff);   \
    if (doA) {                                                                  \
        const bf16* p_ = Ast + (size_t)(kA) * 32;                               \
        gl_lds16(p_,                    &sA[(S) ^ 1][t * 8]);                   \
        gl_lds16(p_ + (size_t)64 * KDIM, &sA[(S) ^ 1][t * 8 + 2048]);           \
    }                                                                           \
    __builtin_amdgcn_s_setprio(1);                                              \
    _Pragma("unroll")                                                           \
    for (int m = 0; m < 2; ++m)                                                 \
        _Pragma("unroll")                                                       \
        for (int n = 0; n < 6; ++n)                                             \
            acc[m][n] = G_MFMA(af[m], bfr[n], acc[m][n]);                       \
    __builtin_amdgcn_s_setprio(0);                                              \
    __builtin_amdgcn_s_barrier();                                               \
    af[0] = *(const bf16x8*)(A8 + (wr * 64 + 32 + lr) * 64 + kxoff);            \
    af[1] = *(const bf16x8*)(A8 + (wr * 64 + 48 + lr) * 64 + kxoff);            \
    if (doB) {                                                                  \
        const bf16* p_ = Wst + (size_t)(kB) * 32;                               \
        gl_lds16(p_,                     &sB[S][t * 8]);                        \
        gl_lds16(p_ + (size_t)64 * KDIM,  &sB[S][t * 8 + 2048]);                \
        gl_lds16(p_ + (size_t)128 * KDIM, &sB[S][t * 8 + 4096]);                \
    }                                                                           \
    __builtin_amdgcn_s_setprio(1);                                              \
    _Pragma("unroll")                                                           \
    for (int m = 0; m < 2; ++m)                                                 \
        _Pragma("unroll")                                                       \
        for (int n = 0; n < 6; ++n)                                             \
            acc[m + 2][n] = G_MFMA(af[m], bfr[n], acc[m + 2][n]);               \
    __builtin_amdgcn_s_setprio(0);                                              \
    if ((vmn) == 3) { VMW(3); } else if ((vmn) == 0) { VMW(0); }                \
    __builtin_amdgcn_s_barrier();                                               \
} while (0)

#define GEMM192_PRE(A_PTR, W_PTR)                                               \
    const int t = threadIdx.x;                                                  \
    const int lane = t & 63;                                                    \
    const int wv = t >> 6;                                                      \
    const int wr = wv >> 1, wc = wv & 1;                                        \
    const int lr = lane & 15, lg = lane >> 4;                                   \
    const int kxoff = (lg << 4) ^ (((lr >> 1) & 3) << 4);                       \
    const int srow = t >> 2;                                                    \
    const int spos = ((t & 3) ^ ((t >> 3) & 3)) * 8;                            \
    const int bm = blockIdx.x, bn = blockIdx.y;                                 \
    const bf16* Ab = (A_PTR) + (size_t)bm * 128 * KDIM;                         \
    const bf16* Wb = (W_PTR) + (size_t)bn * 192 * KDIM;                         \
    const bf16* Ast = Ab + (size_t)srow * KDIM + spos;                          \
    const bf16* Wst = Wb + (size_t)srow * KDIM + spos;                          \
    f32x4 acc[4][6] = {};                                                       \
    gl_lds16(Ast,                     &sA[0][t * 8]);                           \
    gl_lds16(Ast + (size_t)64 * KDIM, &sA[0][t * 8 + 2048]);                    \
    gl_lds16(Wst,                      &sB[0][t * 8]);                          \
    gl_lds16(Wst + (size_t)64 * KDIM,  &sB[0][t * 8 + 2048]);                   \
    gl_lds16(Wst + (size_t)128 * KDIM, &sB[0][t * 8 + 4096]);                   \
    gl_lds16(Wst + 32,                      &sB[1][t * 8]);                     \
    gl_lds16(Wst + 32 + (size_t)64 * KDIM,  &sB[1][t * 8 + 2048]);              \
    gl_lds16(Wst + 32 + (size_t)128 * KDIM, &sB[1][t * 8 + 4096]);              \
    VMW(3);                                                                     \
    __builtin_amdgcn_s_barrier();                                               \
    _Pragma("unroll 1")                                                         \
    for (int g = 0; g < 11; ++g) {                                              \
        QTILE(0, 2 * g + 1, 2 * g + 2, 1, 1, 3);                                \
        QTILE(1, 2 * g + 2, 2 * g + 3, 1, 1, 3);                                \
    }                                                                           \
    QTILE(0, 23, 0, 1, 0, 0);                                                   \
    QTILE(1, 0, 0, 0, 0, -1);

__global__ __launch_bounds__(256, 3) void k_gemm_qkv(
    const bf16* __restrict__ A, const bf16* __restrict__ W,
    bf16* __restrict__ qb, bf16* __restrict__ kb, bf16* __restrict__ vb)
{
    __shared__ __attribute__((aligned(16))) bf16 sA[2][4096];   // 128 rows x 32
    __shared__ __attribute__((aligned(16))) bf16 sB[2][6144];   // 192 rows x 32
    GEMM192_PRE(A, W);

    const float QSC = 0.18033688011112042f;  // 0.125 * log2(e) folded into q
#pragma unroll
    for (int n = 0; n < 6; ++n) {
        int o = bn * 192 + wc * 96 + n * 16 + lr;
        int s = o / 768;
        int rem = o - s * 768;
        int head = rem >> 6;
        int d = o & 63;
        bf16* dst = (s == 0) ? qb : ((s == 1) ? kb : vb);
        float sc = (s == 0) ? QSC : 1.0f;
#pragma unroll
        for (int m = 0; m < 4; ++m) {
            int grow = bm * 128 + wr * 64 + m * 16 + lg * 4;
            int bidx = grow >> 10;
            int tok = grow & 1023;
            size_t base = (((size_t)bidx * NHEAD + head) * NTOK + tok) * HDIM + d;
#pragma unroll
            for (int r = 0; r < 4; ++r)
                dst[base + (size_t)r * HDIM] = (bf16)(acc[m][n][r] * sc);
        }
    }
}

__global__ __launch_bounds__(256, 3) void k_gemm_proj(
    const bf16* __restrict__ A, const bf16* __restrict__ W,
    const float* __restrict__ bias, float* __restrict__ out)
{
    __shared__ __attribute__((aligned(16))) bf16 sA[2][4096];
    __shared__ __attribute__((aligned(16))) bf16 sB[2][6144];
    GEMM192_PRE(A, W);

#pragma unroll
    for (int n = 0; n < 6; ++n) {
        int col = bn * 192 + wc * 96 + n * 16 + lr;
        float bv = bias[col];
#pragma unroll
        for (int m = 0; m < 4; ++m) {
            int grow = bm * 128 + wr * 64 + m * 16 + lg * 4;
#pragma unroll
            for (int r = 0; r < 4; ++r)
                out[(size_t)(grow + r) * KDIM + col] = acc[m][n][r] + bv;
        }
    }
}

// =====================================================================================
// Banded flash attention (64-key steps, static-max softmax: banded logits bounded,
// P = exp2(s) directly — no online max chain; masked entries exactly 0)
// =====================================================================================
__global__ __launch_bounds__(256) void k_attn(
    const bf16* __restrict__ qbuf, const bf16* __restrict__ kbuf,
    const bf16* __restrict__ vbuf, bf16* __restrict__ ob)
{
    const int x = blockIdx.x;
    const int sub = x >> 3;
    const int bh = (x & 7) * 12 + (sub >> 4);   // 12 bh per XCD
    const int qblk = sub & 15;                   // == h_q
    const int head = bh % NHEAD, bidx = bh / NHEAD;
    const bf16* Q  = qbuf + (size_t)bh * NTOK * HDIM;
    const bf16* Kp = kbuf + (size_t)bh * NTOK * HDIM;
    const bf16* Vp = vbuf + (size_t)bh * NTOK * HDIM;

    const int t = threadIdx.x, lane = t & 63, wv = t >> 6;
    const int lr = lane & 15, lg = lane >> 4, lkb = lg * 8;

    __shared__ bf16 Ks[2][64 * 64];   // [key][d], swizzled
    __shared__ bf16 vT[2][64 * 64];   // [d][key], swizzled
    __shared__ bf16 pls[4][16 * 64];  // per-wave P [q][key], swizzled

    {
        bf16x8 z = {};
        *(bf16x8*)&pls[wv][lane * 16] = z;
        *(bf16x8*)&pls[wv][lane * 16 + 8] = z;
    }

    bf16x8 qf[2];
#pragma unroll
    for (int ks = 0; ks < 2; ++ks)
        qf[ks] = *(const bf16x8*)(Q + (size_t)(qblk * 64 + wv * 16 + lr) * HDIM + ks * 32 + lkb);

    f32x4 acc[4] = {};
    float lrow[4] = {0.f, 0.f, 0.f, 0.f};

    const int kh0 = (qblk - 3 < 0) ? 0 : qblk - 3;
    const int kh1 = (qblk + 3 > 15) ? 15 : qblk + 3;

    const int sj = t >> 2;
    const int sd = (t & 3) * 16;

    const bf16* ks0 = Kp + (size_t)(kh0 * 64 + sj) * HDIM + sd;
    const bf16* vs0 = Vp + (size_t)(kh0 * 64 + sj) * HDIM + sd;
    bf16x8 gk0 = *(const bf16x8*)ks0, gk1 = *(const bf16x8*)(ks0 + 8);
    bf16x8 gv0 = *(const bf16x8*)vs0, gv1 = *(const bf16x8*)(vs0 + 8);

    char* pb8 = (char*)pls[wv];
    const int wq0 = wv * 16 + lg * 4;
    int cur = 0;

    for (int kh = kh0; kh <= kh1; ++kh) {
        char* kb8 = (char*)Ks[cur];
        char* vb8 = (char*)vT[cur];
        {
            int kbo = sj * 128 + sd * 2;
            *(bf16x8*)(kb8 + SWZ(sj, kbo)) = gk0;
            *(bf16x8*)(kb8 + SWZ(sj, kbo + 16)) = gk1;
        }
#pragma unroll
        for (int ii = 0; ii < 8; ++ii) {
            int d = sd + ii;
            *(bf16*)(vb8 + SWZ(d, (d << 7) + (sj << 1))) = gv0[ii];
        }
#pragma unroll
        for (int ii = 0; ii < 8; ++ii) {
            int d = sd + 8 + ii;
            *(bf16*)(vb8 + SWZ(d, (d << 7) + (sj << 1))) = gv1[ii];
        }
        if (kh < kh1) {
            const bf16* kn = Kp + (size_t)((kh + 1) * 64 + sj) * HDIM + sd;
            const bf16* vn = Vp + (size_t)((kh + 1) * 64 + sj) * HDIM + sd;
            gk0 = *(const bf16x8*)kn; gk1 = *(const bf16x8*)(kn + 8);
            gv0 = *(const bf16x8*)vn; gv1 = *(const bf16x8*)(vn + 8);
        }
        asm volatile("s_waitcnt lgkmcnt(0)" ::: "memory");
        __builtin_amdgcn_s_barrier();

        // ---- QK^T + P = exp2(s) (static max), accumulate row sums, write P ----
        float psum[4] = {0.f, 0.f, 0.f, 0.f};
#pragma unroll
        for (int jj = 0; jj < 3; ++jj) {
            int j = wv - 1 + jj;
            if (j >= 0 && j <= 3) {        // wave-uniform
                int key = j * 16 + lr;
                int kbase = key * 128;
                bf16x8 kf0 = *(const bf16x8*)(kb8 + SWZ(key, kbase + lg * 16));
                bf16x8 kf1 = *(const bf16x8*)(kb8 + SWZ(key, kbase + 64 + lg * 16));
                f32x4 sv = {};
                sv = G_MFMA(qf[0], kf0, sv);
                sv = G_MFMA(qf[1], kf1, sv);
#pragma unroll
                for (int r = 0; r < 4; ++r) {
                    int dw = wq0 + r - key;
                    float p = (dw >= -5 && dw <= 5) ? exp2f(sv[r]) : 0.0f;
                    psum[r] += p;
                    int row = lg * 4 + r;
                    *(bf16*)(pb8 + SWZ(row, row * 128 + key * 2)) = (bf16)p;
                }
            }
        }
#pragma unroll
        for (int r = 0; r < 4; ++r) lrow[r] += psum[r];

        // ---- PV: A = P[16x64], B = V^T ----
        bf16x8 pf0 = *(const bf16x8*)(pb8 + SWZ(lr, lr * 128 + lg * 16));
        bf16x8 pf1 = *(const bf16x8*)(pb8 + SWZ(lr, lr * 128 + 64 + lg * 16));
#pragma unroll
        for (int dt = 0; dt < 4; ++dt) {
            int vrow = dt * 16 + lr;
            bf16x8 vf0 = *(const bf16x8*)(vb8 + SWZ(vrow, vrow * 128 + lg * 16));
            bf16x8 vf1 = *(const bf16x8*)(vb8 + SWZ(vrow, vrow * 128 + 64 + lg * 16));
            acc[dt] = G_MFMA(pf0, vf0, acc[dt]);
            acc[dt] = G_MFMA(pf1, vf1, acc[dt]);
        }
        cur ^= 1;
    } // kh

    // ---- finalize ----
#pragma unroll
    for (int off = 1; off < 16; off <<= 1)
#pragma unroll
        for (int r = 0; r < 4; ++r) lrow[r] += __shfl_xor(lrow[r], off);

#pragma unroll
    for (int r = 0; r < 4; ++r) {
        float inv = 1.0f / lrow[r];
        int tok = qblk * 64 + wv * 16 + lg * 4 + r;
        size_t rowbase = ((size_t)bidx * NTOK + tok) * KDIM + head * HDIM;
#pragma unroll
        for (int dt = 0; dt < 4; ++dt)
            ob[rowbase + dt * 16 + lr] = (bf16)(acc[dt][r] * inv);
    }
}

// ---------------- launcher ----------------
extern "C" void kernel_launch(void* const* d_in, const int* in_sizes, int n_in,
                              void* d_out, int out_size, void* d_ws, size_t ws_size,
                              hipStream_t stream) {
    const float* x      = (const float*)d_in[0];
    const float* w_qkv  = (const float*)d_in[1];
    const float* w_proj = (const float*)d_in[2];
    const float* b_proj = (const float*)d_in[3];
    float* out = (float*)d_out;

    char* ws = (char*)d_ws;
    bf16* xb  = (bf16*)(ws);                  // 8192*768*2   = 12582912
    bf16* wqb = (bf16*)(ws + 12582912);       // 2304*768*2   =  3538944
    bf16* wpb = (bf16*)(ws + 16121856);       // 768*768*2    =  1179648
    bf16* qb  = (bf16*)(ws + 17301504);       // 96*1024*64*2 = 12582912
    bf16* kb  = (bf16*)(ws + 29884416);
    bf16* vb  = (bf16*)(ws + 42467328);
    bf16* aob = (bf16*)(ws + 55050240);       // attn out bf16 [8192][768]

    hipLaunchKernelGGL(k_cvt_all, dim3(8448), dim3(256), 0, stream, x, w_qkv, w_proj, xb, wqb, wpb);
    hipLaunchKernelGGL(k_gemm_qkv, dim3(64, 12), dim3(256), 0, stream, xb, wqb, qb, kb, vb);
    hipLaunchKernelGGL(k_attn,     dim3(1536), dim3(256), 0, stream, qb, kb, vb, aob);
    hipLaunchKernelGGL(k_gemm_proj, dim3(64, 4), dim3(256), 0, stream, aob, wpb, b_proj, out);
}

// Round 15
// 97.855 us; speedup vs baseline: 1.0890x; 1.0331x over previous
//
#include <hip/hip_runtime.h>
#include <hip/hip_bf16.h>
#include <stdint.h>

typedef __bf16 bf16;
typedef __bf16 bf16x8 __attribute__((ext_vector_type(8)));
typedef __bf16 bf16x4 __attribute__((ext_vector_type(4)));
typedef float f32x4 __attribute__((ext_vector_type(4)));

#define KDIM 768
#define NHEAD 12
#define HDIM 64
#define NTOK 1024
#define BATCH 8

// XOR swizzle for row-major [row][128B-row] LDS tiles (attention)
#define SWZ(row, b) ((b) ^ (((row) & 7) << 4))

__device__ __forceinline__ void gl_lds16(const bf16* g, bf16* l) {
    __builtin_amdgcn_global_load_lds((const __attribute__((address_space(1))) void*)g,
                                     (__attribute__((address_space(3))) void*)l, 16, 0, 0);
}

#define G_MFMA(a, b, c) __builtin_amdgcn_mfma_f32_16x16x32_bf16(a, b, c, 0, 0, 0)
#define VMW(N) asm volatile("s_waitcnt vmcnt(" #N ")" ::: "memory")

// ---------------- fp32 -> bf16 convert (all three tensors, one launch) ----------------
__global__ void k_cvt_all(const float* __restrict__ x, const float* __restrict__ wq,
                          const float* __restrict__ wp, bf16* __restrict__ xb,
                          bf16* __restrict__ wqb, bf16* __restrict__ wpb) {
    int b = blockIdx.x;
    const float* src;
    bf16* dst;
    int base;
    if (b < 6144)       { src = x;  dst = xb;  base = b; }
    else if (b < 7872)  { src = wq; dst = wqb; base = b - 6144; }
    else                { src = wp; dst = wpb; base = b - 7872; }
    int i = (base * 256 + threadIdx.x) * 4;
    float4 v = *(const float4*)(src + i);
    bf16x4 o;
    o[0] = (bf16)v.x; o[1] = (bf16)v.y; o[2] = (bf16)v.z; o[3] = (bf16)v.w;
    *(bf16x4*)(dst + i) = o;
}

// =====================================================================================
// QKV GEMM — BK=64 fine-phase: 128(M) x 192(N) x K, 12 K-tiles, 4 waves (2x2),
// per-wave 64x96 (acc[4][6], 48 MFMA/tile). 2-slot LDS (A 2x16KB + B 2x24KB = 80KB,
// 2 blocks/CU). All staging writes target slot s^1 (never the live slot) -> NO
// mid-tile barrier; ONE vmcnt(0)+barrier per 48-MFMA tile (half the drain events,
// 2x the issue-to-drain cover vs BK=32). 128B LDS rows, XOR swizzle byte^=(row&7)<<4
// (r4-proj layout, measured 0 conflicts); pre-swizzled global source for the
// lane-linear global_load_lds destination.
// =====================================================================================

#define TILE64(S, kt) do {                                                      \
    const char* A8 = (const char*)sA[S];                                        \
    const char* B8 = (const char*)sB[S];                                        \
    bf16x8 af[4], bfr[6];                                                       \
    _Pragma("unroll")                                                           \
    for (int m = 0; m < 4; ++m)                                                 \
        af[m] = *(const bf16x8*)(A8 + (wr * 64 + m * 16 + lr) * 128 + k0off);   \
    _Pragma("unroll")                                                           \
    for (int n = 0; n < 6; ++n)                                                 \
        bfr[n] = *(const bf16x8*)(B8 + (wc * 96 + n * 16 + lr) * 128 + k0off);  \
    if ((kt) < 11) {                                                            \
        const bf16* p_ = Ast + (size_t)((kt) + 1) * 64;                         \
        gl_lds16(p_,                      &sA[(S) ^ 1][t * 8]);                 \
        gl_lds16(p_ + (size_t)32 * KDIM,  &sA[(S) ^ 1][t * 8 + 2048]);          \
        gl_lds16(p_ + (size_t)64 * KDIM,  &sA[(S) ^ 1][t * 8 + 4096]);          \
        gl_lds16(p_ + (size_t)96 * KDIM,  &sA[(S) ^ 1][t * 8 + 6144]);          \
    }                                                                           \
    __builtin_amdgcn_s_setprio(1);                                              \
    _Pragma("unroll")                                                           \
    for (int m = 0; m < 4; ++m)                                                 \
        _Pragma("unroll")                                                       \
        for (int n = 0; n < 6; ++n)                                             \
            acc[m][n] = G_MFMA(af[m], bfr[n], acc[m][n]);                       \
    __builtin_amdgcn_s_setprio(0);                                              \
    _Pragma("unroll")                                                           \
    for (int m = 0; m < 4; ++m)                                                 \
        af[m] = *(const bf16x8*)(A8 + (wr * 64 + m * 16 + lr) * 128 + k1off);   \
    _Pragma("unroll")                                                           \
    for (int n = 0; n < 6; ++n)                                                 \
        bfr[n] = *(const bf16x8*)(B8 + (wc * 96 + n * 16 + lr) * 128 + k1off);  \
    if ((kt) < 11) {                                                            \
        const bf16* p_ = Wst + (size_t)((kt) + 1) * 64;                         \
        gl_lds16(p_,                       &sB[(S) ^ 1][t * 8]);                \
        gl_lds16(p_ + (size_t)32 * KDIM,   &sB[(S) ^ 1][t * 8 + 2048]);         \
        gl_lds16(p_ + (size_t)64 * KDIM,   &sB[(S) ^ 1][t * 8 + 4096]);         \
        gl_lds16(p_ + (size_t)96 * KDIM,   &sB[(S) ^ 1][t * 8 + 6144]);         \
        gl_lds16(p_ + (size_t)128 * KDIM,  &sB[(S) ^ 1][t * 8 + 8192]);         \
        gl_lds16(p_ + (size_t)160 * KDIM,  &sB[(S) ^ 1][t * 8 + 10240]);        \
    }                                                                           \
    __builtin_amdgcn_s_setprio(1);                                              \
    _Pragma("unroll")                                                           \
    for (int m = 0; m < 4; ++m)                                                 \
        _Pragma("unroll")                                                       \
        for (int n = 0; n < 6; ++n)                                             \
            acc[m][n] = G_MFMA(af[m], bfr[n], acc[m][n]);                       \
    __builtin_amdgcn_s_setprio(0);                                              \
    VMW(0);                                                                     \
    __builtin_amdgcn_s_barrier();                                               \
} while (0)

__global__ __launch_bounds__(256, 2) void k_gemm_qkv(
    const bf16* __restrict__ A, const bf16* __restrict__ W,
    bf16* __restrict__ qb, bf16* __restrict__ kb, bf16* __restrict__ vb)
{
    __shared__ __attribute__((aligned(16))) bf16 sA[2][8192];    // 128 rows x 64
    __shared__ __attribute__((aligned(16))) bf16 sB[2][12288];   // 192 rows x 64
    const int t = threadIdx.x;
    const int lane = t & 63;
    const int wv = t >> 6;
    const int wr = wv >> 1, wc = wv & 1;
    const int lr = lane & 15, lg = lane >> 4;
    const int xorb = (lr & 7) << 4;
    const int k0off = (lg << 4) ^ xorb;
    const int k1off = (64 + (lg << 4)) ^ xorb;
    const int spos = ((t & 7) ^ ((t >> 3) & 7)) * 8;   // pre-swizzled src k-chunk
    const int bm = blockIdx.x, bn = blockIdx.y;
    const bf16* Ast = A + (size_t)(bm * 128 + (t >> 3)) * KDIM + spos;
    const bf16* Wst = W + (size_t)(bn * 192 + (t >> 3)) * KDIM + spos;
    f32x4 acc[4][6] = {};

    // prologue: stage tile 0 into slot 0 (A 4 + B 6 loads), drain, barrier
    gl_lds16(Ast,                      &sA[0][t * 8]);
    gl_lds16(Ast + (size_t)32 * KDIM,  &sA[0][t * 8 + 2048]);
    gl_lds16(Ast + (size_t)64 * KDIM,  &sA[0][t * 8 + 4096]);
    gl_lds16(Ast + (size_t)96 * KDIM,  &sA[0][t * 8 + 6144]);
    gl_lds16(Wst,                       &sB[0][t * 8]);
    gl_lds16(Wst + (size_t)32 * KDIM,   &sB[0][t * 8 + 2048]);
    gl_lds16(Wst + (size_t)64 * KDIM,   &sB[0][t * 8 + 4096]);
    gl_lds16(Wst + (size_t)96 * KDIM,   &sB[0][t * 8 + 6144]);
    gl_lds16(Wst + (size_t)128 * KDIM,  &sB[0][t * 8 + 8192]);
    gl_lds16(Wst + (size_t)160 * KDIM,  &sB[0][t * 8 + 10240]);
    VMW(0);
    __builtin_amdgcn_s_barrier();

#pragma unroll 1
    for (int g = 0; g < 6; ++g) {
        TILE64(0, g * 2);
        TILE64(1, g * 2 + 1);
    }

    const float QSC = 0.18033688011112042f;  // 0.125 * log2(e) folded into q
#pragma unroll
    for (int n = 0; n < 6; ++n) {
        int o = bn * 192 + wc * 96 + n * 16 + lr;
        int s = o / 768;
        int rem = o - s * 768;
        int head = rem >> 6;
        int d = o & 63;
        bf16* dst = (s == 0) ? qb : ((s == 1) ? kb : vb);
        float sc = (s == 0) ? QSC : 1.0f;
#pragma unroll
        for (int m = 0; m < 4; ++m) {
            int grow = bm * 128 + wr * 64 + m * 16 + lg * 4;
            int bidx = grow >> 10;
            int tok = grow & 1023;
            size_t base = (((size_t)bidx * NHEAD + head) * NTOK + tok) * HDIM + d;
#pragma unroll
            for (int r = 0; r < 4; ++r)
                dst[base + (size_t)r * HDIM] = (bf16)(acc[m][n][r] * sc);
        }
    }
}

// =====================================================================================
// Proj GEMM: r14-exact fine-phase BK=32 path (verified ~14us)
// =====================================================================================
#define QTILE(S, kA, kB, doA, doB, vmn) do {                                    \
    const char* A8 = (const char*)sA[S];                                        \
    const char* B8 = (const char*)sB[S];                                        \
    bf16x8 af[2], bfr[6];                                                       \
    af[0] = *(const bf16x8*)(A8 + (wr * 64 + 0 + lr) * 64 + kxoff);             \
    af[1] = *(const bf16x8*)(A8 + (wr * 64 + 16 + lr) * 64 + kxoff);            \
    _Pragma("unroll")                                                           \
    for (int n = 0; n < 6; ++n)                                                 \
        bfr[n] = *(const bf16x8*)(B8 + (wc * 96 + n * 16 + lr) * 64 + kxoff);   \
    if (doA) {                                                                  \
        const bf16* p_ = Ast + (size_t)(kA) * 32;                               \
        gl_lds16(p_,                    &sA[(S) ^ 1][t * 8]);                   \
        gl_lds16(p_ + (size_t)64 * KDIM, &sA[(S) ^ 1][t * 8 + 2048]);           \
    }                                                                           \
    __builtin_amdgcn_s_setprio(1);                                              \
    _Pragma("unroll")                                                           \
    for (int m = 0; m < 2; ++m)                                                 \
        _Pragma("unroll")                                                       \
        for (int n = 0; n < 6; ++n)                                             \
            acc[m][n] = G_MFMA(af[m], bfr[n], acc[m][n]);                       \
    __builtin_amdgcn_s_setprio(0);                                              \
    __builtin_amdgcn_s_barrier();                                               \
    af[0] = *(const bf16x8*)(A8 + (wr * 64 + 32 + lr) * 64 + kxoff);            \
    af[1] = *(const bf16x8*)(A8 + (wr * 64 + 48 + lr) * 64 + kxoff);            \
    if (doB) {                                                                  \
        const bf16* p_ = Wst + (size_t)(kB) * 32;                               \
        gl_lds16(p_,                     &sB[S][t * 8]);                        \
        gl_lds16(p_ + (size_t)64 * KDIM,  &sB[S][t * 8 + 2048]);                \
        gl_lds16(p_ + (size_t)128 * KDIM, &sB[S][t * 8 + 4096]);                \
    }                                                                           \
    __builtin_amdgcn_s_setprio(1);                                              \
    _Pragma("unroll")                                                           \
    for (int m = 0; m < 2; ++m)                                                 \
        _Pragma("unroll")                                                       \
        for (int n = 0; n < 6; ++n)                                             \
            acc[m + 2][n] = G_MFMA(af[m], bfr[n], acc[m + 2][n]);               \
    __builtin_amdgcn_s_setprio(0);                                              \
    if ((vmn) == 3) { VMW(3); } else if ((vmn) == 0) { VMW(0); }                \
    __builtin_amdgcn_s_barrier();                                               \
} while (0)

__global__ __launch_bounds__(256, 3) void k_gemm_proj(
    const bf16* __restrict__ A, const bf16* __restrict__ W,
    const float* __restrict__ bias, float* __restrict__ out)
{
    __shared__ __attribute__((aligned(16))) bf16 sA[2][4096];
    __shared__ __attribute__((aligned(16))) bf16 sB[2][6144];
    const int t = threadIdx.x;
    const int lane = t & 63;
    const int wv = t >> 6;
    const int wr = wv >> 1, wc = wv & 1;
    const int lr = lane & 15, lg = lane >> 4;
    const int kxoff = (lg << 4) ^ (((lr >> 1) & 3) << 4);
    const int srow = t >> 2;
    const int spos = ((t & 3) ^ ((t >> 3) & 3)) * 8;
    const int bm = blockIdx.x, bn = blockIdx.y;
    const bf16* Ab = A + (size_t)bm * 128 * KDIM;
    const bf16* Wb = W + (size_t)bn * 192 * KDIM;
    const bf16* Ast = Ab + (size_t)srow * KDIM + spos;
    const bf16* Wst = Wb + (size_t)srow * KDIM + spos;
    f32x4 acc[4][6] = {};
    gl_lds16(Ast,                     &sA[0][t * 8]);
    gl_lds16(Ast + (size_t)64 * KDIM, &sA[0][t * 8 + 2048]);
    gl_lds16(Wst,                      &sB[0][t * 8]);
    gl_lds16(Wst + (size_t)64 * KDIM,  &sB[0][t * 8 + 2048]);
    gl_lds16(Wst + (size_t)128 * KDIM, &sB[0][t * 8 + 4096]);
    gl_lds16(Wst + 32,                      &sB[1][t * 8]);
    gl_lds16(Wst + 32 + (size_t)64 * KDIM,  &sB[1][t * 8 + 2048]);
    gl_lds16(Wst + 32 + (size_t)128 * KDIM, &sB[1][t * 8 + 4096]);
    VMW(3);
    __builtin_amdgcn_s_barrier();
#pragma unroll 1
    for (int g = 0; g < 11; ++g) {
        QTILE(0, 2 * g + 1, 2 * g + 2, 1, 1, 3);
        QTILE(1, 2 * g + 2, 2 * g + 3, 1, 1, 3);
    }
    QTILE(0, 23, 0, 1, 0, 0);
    QTILE(1, 0, 0, 0, 0, -1);

#pragma unroll
    for (int n = 0; n < 6; ++n) {
        int col = bn * 192 + wc * 96 + n * 16 + lr;
        float bv = bias[col];
#pragma unroll
        for (int m = 0; m < 4; ++m) {
            int grow = bm * 128 + wr * 64 + m * 16 + lg * 4;
#pragma unroll
            for (int r = 0; r < 4; ++r)
                out[(size_t)(grow + r) * KDIM + col] = acc[m][n][r] + bv;
        }
    }
}

// =====================================================================================
// Banded flash attention (r14-exact: 64-key steps, static-max softmax)
// =====================================================================================
__global__ __launch_bounds__(256) void k_attn(
    const bf16* __restrict__ qbuf, const bf16* __restrict__ kbuf,
    const bf16* __restrict__ vbuf, bf16* __restrict__ ob)
{
    const int x = blockIdx.x;
    const int sub = x >> 3;
    const int bh = (x & 7) * 12 + (sub >> 4);   // 12 bh per XCD
    const int qblk = sub & 15;                   // == h_q
    const int head = bh % NHEAD, bidx = bh / NHEAD;
    const bf16* Q  = qbuf + (size_t)bh * NTOK * HDIM;
    const bf16* Kp = kbuf + (size_t)bh * NTOK * HDIM;
    const bf16* Vp = vbuf + (size_t)bh * NTOK * HDIM;

    const int t = threadIdx.x, lane = t & 63, wv = t >> 6;
    const int lr = lane & 15, lg = lane >> 4, lkb = lg * 8;

    __shared__ bf16 Ks[2][64 * 64];   // [key][d], swizzled
    __shared__ bf16 vT[2][64 * 64];   // [d][key], swizzled
    __shared__ bf16 pls[4][16 * 64];  // per-wave P [q][key], swizzled

    {
        bf16x8 z = {};
        *(bf16x8*)&pls[wv][lane * 16] = z;
        *(bf16x8*)&pls[wv][lane * 16 + 8] = z;
    }

    bf16x8 qf[2];
#pragma unroll
    for (int ks = 0; ks < 2; ++ks)
        qf[ks] = *(const bf16x8*)(Q + (size_t)(qblk * 64 + wv * 16 + lr) * HDIM + ks * 32 + lkb);

    f32x4 acc[4] = {};
    float lrow[4] = {0.f, 0.f, 0.f, 0.f};

    const int kh0 = (qblk - 3 < 0) ? 0 : qblk - 3;
    const int kh1 = (qblk + 3 > 15) ? 15 : qblk + 3;

    const int sj = t >> 2;
    const int sd = (t & 3) * 16;

    const bf16* ks0 = Kp + (size_t)(kh0 * 64 + sj) * HDIM + sd;
    const bf16* vs0 = Vp + (size_t)(kh0 * 64 + sj) * HDIM + sd;
    bf16x8 gk0 = *(const bf16x8*)ks0, gk1 = *(const bf16x8*)(ks0 + 8);
    bf16x8 gv0 = *(const bf16x8*)vs0, gv1 = *(const bf16x8*)(vs0 + 8);

    char* pb8 = (char*)pls[wv];
    const int wq0 = wv * 16 + lg * 4;
    int cur = 0;

    for (int kh = kh0; kh <= kh1; ++kh) {
        char* kb8 = (char*)Ks[cur];
        char* vb8 = (char*)vT[cur];
        {
            int kbo = sj * 128 + sd * 2;
            *(bf16x8*)(kb8 + SWZ(sj, kbo)) = gk0;
            *(bf16x8*)(kb8 + SWZ(sj, kbo + 16)) = gk1;
        }
#pragma unroll
        for (int ii = 0; ii < 8; ++ii) {
            int d = sd + ii;
            *(bf16*)(vb8 + SWZ(d, (d << 7) + (sj << 1))) = gv0[ii];
        }
#pragma unroll
        for (int ii = 0; ii < 8; ++ii) {
            int d = sd + 8 + ii;
            *(bf16*)(vb8 + SWZ(d, (d << 7) + (sj << 1))) = gv1[ii];
        }
        if (kh < kh1) {
            const bf16* kn = Kp + (size_t)((kh + 1) * 64 + sj) * HDIM + sd;
            const bf16* vn = Vp + (size_t)((kh + 1) * 64 + sj) * HDIM + sd;
            gk0 = *(const bf16x8*)kn; gk1 = *(const bf16x8*)(kn + 8);
            gv0 = *(const bf16x8*)vn; gv1 = *(const bf16x8*)(vn + 8);
        }
        asm volatile("s_waitcnt lgkmcnt(0)" ::: "memory");
        __builtin_amdgcn_s_barrier();

        // ---- QK^T + P = exp2(s) (static max), accumulate row sums, write P ----
        float psum[4] = {0.f, 0.f, 0.f, 0.f};
#pragma unroll
        for (int jj = 0; jj < 3; ++jj) {
            int j = wv - 1 + jj;
            if (j >= 0 && j <= 3) {        // wave-uniform
                int key = j * 16 + lr;
                int kbase = key * 128;
                bf16x8 kf0 = *(const bf16x8*)(kb8 + SWZ(key, kbase + lg * 16));
                bf16x8 kf1 = *(const bf16x8*)(kb8 + SWZ(key, kbase + 64 + lg * 16));
                f32x4 sv = {};
                sv = G_MFMA(qf[0], kf0, sv);
                sv = G_MFMA(qf[1], kf1, sv);
#pragma unroll
                for (int r = 0; r < 4; ++r) {
                    int dw = wq0 + r - key;
                    float p = (dw >= -5 && dw <= 5) ? exp2f(sv[r]) : 0.0f;
                    psum[r] += p;
                    int row = lg * 4 + r;
                    *(bf16*)(pb8 + SWZ(row, row * 128 + key * 2)) = (bf16)p;
                }
            }
        }
#pragma unroll
        for (int r = 0; r < 4; ++r) lrow[r] += psum[r];

        // ---- PV: A = P[16x64], B = V^T ----
        bf16x8 pf0 = *(const bf16x8*)(pb8 + SWZ(lr, lr * 128 + lg * 16));
        bf16x8 pf1 = *(const bf16x8*)(pb8 + SWZ(lr, lr * 128 + 64 + lg * 16));
#pragma unroll
        for (int dt = 0; dt < 4; ++dt) {
            int vrow = dt * 16 + lr;
            bf16x8 vf0 = *(const bf16x8*)(vb8 + SWZ(vrow, vrow * 128 + lg * 16));
            bf16x8 vf1 = *(const bf16x8*)(vb8 + SWZ(vrow, vrow * 128 + 64 + lg * 16));
            acc[dt] = G_MFMA(pf0, vf0, acc[dt]);
            acc[dt] = G_MFMA(pf1, vf1, acc[dt]);
        }
        cur ^= 1;
    } // kh

    // ---- finalize ----
#pragma unroll
    for (int off = 1; off < 16; off <<= 1)
#pragma unroll
        for (int r = 0; r < 4; ++r) lrow[r] += __shfl_xor(lrow[r], off);

#pragma unroll
    for (int r = 0; r < 4; ++r) {
        float inv = 1.0f / lrow[r];
        int tok = qblk * 64 + wv * 16 + lg * 4 + r;
        size_t rowbase = ((size_t)bidx * NTOK + tok) * KDIM + head * HDIM;
#pragma unroll
        for (int dt = 0; dt < 4; ++dt)
            ob[rowbase + dt * 16 + lr] = (bf16)(acc[dt][r] * inv);
    }
}

// ---------------- launcher ----------------
extern "C" void kernel_launch(void* const* d_in, const int* in_sizes, int n_in,
                              void* d_out, int out_size, void* d_ws, size_t ws_size,
                              hipStream_t stream) {
    const float* x      = (const float*)d_in[0];
    const float* w_qkv  = (const float*)d_in[1];
    const float* w_proj = (const float*)d_in[2];
    const float* b_proj = (const float*)d_in[3];
    float* out = (float*)d_out;

    char* ws = (char*)d_ws;
    bf16* xb  = (bf16*)(ws);                  // 8192*768*2   = 12582912
    bf16* wqb = (bf16*)(ws + 12582912);       // 2304*768*2   =  3538944
    bf16* wpb = (bf16*)(ws + 16121856);       // 768*768*2    =  1179648
    bf16* qb  = (bf16*)(ws + 17301504);       // 96*1024*64*2 = 12582912
    bf16* kb  = (bf16*)(ws + 29884416);
    bf16* vb  = (bf16*)(ws + 42467328);
    bf16* aob = (bf16*)(ws + 55050240);       // attn out bf16 [8192][768]

    hipLaunchKernelGGL(k_cvt_all, dim3(8448), dim3(256), 0, stream, x, w_qkv, w_proj, xb, wqb, wpb);
    hipLaunchKernelGGL(k_gemm_qkv, dim3(64, 12), dim3(256), 0, stream, xb, wqb, qb, kb, vb);
    hipLaunchKernelGGL(k_attn,     dim3(1536), dim3(256), 0, stream, qb, kb, vb, aob);
    hipLaunchKernelGGL(k_gemm_proj, dim3(64, 4), dim3(256), 0, stream, aob, wpb, b_proj, out);
}

// Round 16
// 91.195 us; speedup vs baseline: 1.1685x; 1.0730x over previous
//
#include <hip/hip_runtime.h>
#include <hip/hip_bf16.h>
#include <stdint.h>

typedef __bf16 bf16;
typedef __bf16 bf16x8 __attribute__((ext_vector_type(8)));
typedef __bf16 bf16x4 __attribute__((ext_vector_type(4)));
typedef float f32x4 __attribute__((ext_vector_type(4)));

#define KDIM 768
#define NHEAD 12
#define HDIM 64
#define NTOK 1024
#define BATCH 8

// XOR swizzle for row-major [row][128B-row] LDS tiles (attention)
#define SWZ(row, b) ((b) ^ (((row) & 7) << 4))

__device__ __forceinline__ void gl_lds16(const bf16* g, bf16* l) {
    __builtin_amdgcn_global_load_lds((const __attribute__((address_space(1))) void*)g,
                                     (__attribute__((address_space(3))) void*)l, 16, 0, 0);
}

#define G_MFMA(a, b, c) __builtin_amdgcn_mfma_f32_16x16x32_bf16(a, b, c, 0, 0, 0)
#define VMW(N) asm volatile("s_waitcnt vmcnt(" #N ")" ::: "memory")

// ---------------- fp32 -> bf16 convert (all three tensors, one launch) ----------------
__global__ void k_cvt_all(const float* __restrict__ x, const float* __restrict__ wq,
                          const float* __restrict__ wp, bf16* __restrict__ xb,
                          bf16* __restrict__ wqb, bf16* __restrict__ wpb) {
    int b = blockIdx.x;
    const float* src;
    bf16* dst;
    int base;
    if (b < 6144)       { src = x;  dst = xb;  base = b; }
    else if (b < 7872)  { src = wq; dst = wqb; base = b - 6144; }
    else                { src = wp; dst = wpb; base = b - 7872; }
    int i = (base * 256 + threadIdx.x) * 4;
    float4 v = *(const float4*)(src + i);
    bf16x4 o;
    o[0] = (bf16)v.x; o[1] = (bf16)v.y; o[2] = (bf16)v.z; o[3] = (bf16)v.w;
    *(bf16x4*)(dst + i) = o;
}

// =====================================================================================
// BK=64 fine-phase GEMM (r15-verified on qkv): 128(M) x 192(N) x K, 12 K-tiles,
// 4 waves (2x2), per-wave 64x96 (acc[4][6], 48 MFMA/tile). 2-slot LDS (80KB,
// 2 blocks/CU). All staging writes target slot s^1 -> NO mid-tile barrier; ONE
// vmcnt(0)+barrier per 48-MFMA tile. 128B LDS rows, XOR swizzle byte^=(row&7)<<4,
// pre-swizzled global source for the lane-linear global_load_lds destination.
// =====================================================================================

#define TILE64(S, kt) do {                                                      \
    const char* A8 = (const char*)sA[S];                                        \
    const char* B8 = (const char*)sB[S];                                        \
    bf16x8 af[4], bfr[6];                                                       \
    _Pragma("unroll")                                                           \
    for (int m = 0; m < 4; ++m)                                                 \
        af[m] = *(const bf16x8*)(A8 + (wr * 64 + m * 16 + lr) * 128 + k0off);   \
    _Pragma("unroll")                                                           \
    for (int n = 0; n < 6; ++n)                                                 \
        bfr[n] = *(const bf16x8*)(B8 + (wc * 96 + n * 16 + lr) * 128 + k0off);  \
    if ((kt) < 11) {                                                            \
        const bf16* p_ = Ast + (size_t)((kt) + 1) * 64;                         \
        gl_lds16(p_,                      &sA[(S) ^ 1][t * 8]);                 \
        gl_lds16(p_ + (size_t)32 * KDIM,  &sA[(S) ^ 1][t * 8 + 2048]);          \
        gl_lds16(p_ + (size_t)64 * KDIM,  &sA[(S) ^ 1][t * 8 + 4096]);          \
        gl_lds16(p_ + (size_t)96 * KDIM,  &sA[(S) ^ 1][t * 8 + 6144]);          \
    }                                                                           \
    __builtin_amdgcn_s_setprio(1);                                              \
    _Pragma("unroll")                                                           \
    for (int m = 0; m < 4; ++m)                                                 \
        _Pragma("unroll")                                                       \
        for (int n = 0; n < 6; ++n)                                             \
            acc[m][n] = G_MFMA(af[m], bfr[n], acc[m][n]);                       \
    __builtin_amdgcn_s_setprio(0);                                              \
    _Pragma("unroll")                                                           \
    for (int m = 0; m < 4; ++m)                                                 \
        af[m] = *(const bf16x8*)(A8 + (wr * 64 + m * 16 + lr) * 128 + k1off);   \
    _Pragma("unroll")                                                           \
    for (int n = 0; n < 6; ++n)                                                 \
        bfr[n] = *(const bf16x8*)(B8 + (wc * 96 + n * 16 + lr) * 128 + k1off);  \
    if ((kt) < 11) {                                                            \
        const bf16* p_ = Wst + (size_t)((kt) + 1) * 64;                         \
        gl_lds16(p_,                       &sB[(S) ^ 1][t * 8]);                \
        gl_lds16(p_ + (size_t)32 * KDIM,   &sB[(S) ^ 1][t * 8 + 2048]);         \
        gl_lds16(p_ + (size_t)64 * KDIM,   &sB[(S) ^ 1][t * 8 + 4096]);         \
        gl_lds16(p_ + (size_t)96 * KDIM,   &sB[(S) ^ 1][t * 8 + 6144]);         \
        gl_lds16(p_ + (size_t)128 * KDIM,  &sB[(S) ^ 1][t * 8 + 8192]);         \
        gl_lds16(p_ + (size_t)160 * KDIM,  &sB[(S) ^ 1][t * 8 + 10240]);        \
    }                                                                           \
    __builtin_amdgcn_s_setprio(1);                                              \
    _Pragma("unroll")                                                           \
    for (int m = 0; m < 4; ++m)                                                 \
        _Pragma("unroll")                                                       \
        for (int n = 0; n < 6; ++n)                                             \
            acc[m][n] = G_MFMA(af[m], bfr[n], acc[m][n]);                       \
    __builtin_amdgcn_s_setprio(0);                                              \
    VMW(0);                                                                     \
    __builtin_amdgcn_s_barrier();                                               \
} while (0)

#define GEMM64_PRE(A_PTR, W_PTR)                                                \
    const int t = threadIdx.x;                                                  \
    const int lane = t & 63;                                                    \
    const int wv = t >> 6;                                                      \
    const int wr = wv >> 1, wc = wv & 1;                                        \
    const int lr = lane & 15, lg = lane >> 4;                                   \
    const int xorb = (lr & 7) << 4;                                             \
    const int k0off = (lg << 4) ^ xorb;                                         \
    const int k1off = (64 + (lg << 4)) ^ xorb;                                  \
    const int spos = ((t & 7) ^ ((t >> 3) & 7)) * 8;                            \
    const int bm = blockIdx.x, bn = blockIdx.y;                                 \
    const bf16* Ast = (A_PTR) + (size_t)(bm * 128 + (t >> 3)) * KDIM + spos;    \
    const bf16* Wst = (W_PTR) + (size_t)(bn * 192 + (t >> 3)) * KDIM + spos;    \
    f32x4 acc[4][6] = {};                                                       \
    gl_lds16(Ast,                      &sA[0][t * 8]);                          \
    gl_lds16(Ast + (size_t)32 * KDIM,  &sA[0][t * 8 + 2048]);                   \
    gl_lds16(Ast + (size_t)64 * KDIM,  &sA[0][t * 8 + 4096]);                   \
    gl_lds16(Ast + (size_t)96 * KDIM,  &sA[0][t * 8 + 6144]);                   \
    gl_lds16(Wst,                       &sB[0][t * 8]);                         \
    gl_lds16(Wst + (size_t)32 * KDIM,   &sB[0][t * 8 + 2048]);                  \
    gl_lds16(Wst + (size_t)64 * KDIM,   &sB[0][t * 8 + 4096]);                  \
    gl_lds16(Wst + (size_t)96 * KDIM,   &sB[0][t * 8 + 6144]);                  \
    gl_lds16(Wst + (size_t)128 * KDIM,  &sB[0][t * 8 + 8192]);                  \
    gl_lds16(Wst + (size_t)160 * KDIM,  &sB[0][t * 8 + 10240]);                 \
    VMW(0);                                                                     \
    __builtin_amdgcn_s_barrier();                                               \
    _Pragma("unroll 1")                                                         \
    for (int g = 0; g < 6; ++g) {                                               \
        TILE64(0, g * 2);                                                       \
        TILE64(1, g * 2 + 1);                                                   \
    }

__global__ __launch_bounds__(256, 2) void k_gemm_qkv(
    const bf16* __restrict__ A, const bf16* __restrict__ W,
    bf16* __restrict__ qb, bf16* __restrict__ kb, bf16* __restrict__ vb)
{
    __shared__ __attribute__((aligned(16))) bf16 sA[2][8192];    // 128 rows x 64
    __shared__ __attribute__((aligned(16))) bf16 sB[2][12288];   // 192 rows x 64
    GEMM64_PRE(A, W);

    const float QSC = 0.18033688011112042f;  // 0.125 * log2(e) folded into q
#pragma unroll
    for (int n = 0; n < 6; ++n) {
        int o = bn * 192 + wc * 96 + n * 16 + lr;
        int s = o / 768;
        int rem = o - s * 768;
        int head = rem >> 6;
        int d = o & 63;
        bf16* dst = (s == 0) ? qb : ((s == 1) ? kb : vb);
        float sc = (s == 0) ? QSC : 1.0f;
#pragma unroll
        for (int m = 0; m < 4; ++m) {
            int grow = bm * 128 + wr * 64 + m * 16 + lg * 4;
            int bidx = grow >> 10;
            int tok = grow & 1023;
            size_t base = (((size_t)bidx * NHEAD + head) * NTOK + tok) * HDIM + d;
#pragma unroll
            for (int r = 0; r < 4; ++r)
                dst[base + (size_t)r * HDIM] = (bf16)(acc[m][n][r] * sc);
        }
    }
}

__global__ __launch_bounds__(256, 2) void k_gemm_proj(
    const bf16* __restrict__ A, const bf16* __restrict__ W,
    const float* __restrict__ bias, float* __restrict__ out)
{
    __shared__ __attribute__((aligned(16))) bf16 sA[2][8192];
    __shared__ __attribute__((aligned(16))) bf16 sB[2][12288];
    GEMM64_PRE(A, W);

#pragma unroll
    for (int n = 0; n < 6; ++n) {
        int col = bn * 192 + wc * 96 + n * 16 + lr;
        float bv = bias[col];
#pragma unroll
        for (int m = 0; m < 4; ++m) {
            int grow = bm * 128 + wr * 64 + m * 16 + lg * 4;
#pragma unroll
            for (int r = 0; r < 4; ++r)
                out[(size_t)(grow + r) * KDIM + col] = acc[m][n][r] + bv;
        }
    }
}

// =====================================================================================
// Banded flash attention (r14-exact: 64-key steps, static-max softmax)
// =====================================================================================
__global__ __launch_bounds__(256) void k_attn(
    const bf16* __restrict__ qbuf, const bf16* __restrict__ kbuf,
    const bf16* __restrict__ vbuf, bf16* __restrict__ ob)
{
    const int x = blockIdx.x;
    const int sub = x >> 3;
    const int bh = (x & 7) * 12 + (sub >> 4);   // 12 bh per XCD
    const int qblk = sub & 15;                   // == h_q
    const int head = bh % NHEAD, bidx = bh / NHEAD;
    const bf16* Q  = qbuf + (size_t)bh * NTOK * HDIM;
    const bf16* Kp = kbuf + (size_t)bh * NTOK * HDIM;
    const bf16* Vp = vbuf + (size_t)bh * NTOK * HDIM;

    const int t = threadIdx.x, lane = t & 63, wv = t >> 6;
    const int lr = lane & 15, lg = lane >> 4, lkb = lg * 8;

    __shared__ bf16 Ks[2][64 * 64];   // [key][d], swizzled
    __shared__ bf16 vT[2][64 * 64];   // [d][key], swizzled
    __shared__ bf16 pls[4][16 * 64];  // per-wave P [q][key], swizzled

    {
        bf16x8 z = {};
        *(bf16x8*)&pls[wv][lane * 16] = z;
        *(bf16x8*)&pls[wv][lane * 16 + 8] = z;
    }

    bf16x8 qf[2];
#pragma unroll
    for (int ks = 0; ks < 2; ++ks)
        qf[ks] = *(const bf16x8*)(Q + (size_t)(qblk * 64 + wv * 16 + lr) * HDIM + ks * 32 + lkb);

    f32x4 acc[4] = {};
    float lrow[4] = {0.f, 0.f, 0.f, 0.f};

    const int kh0 = (qblk - 3 < 0) ? 0 : qblk - 3;
    const int kh1 = (qblk + 3 > 15) ? 15 : qblk + 3;

    const int sj = t >> 2;
    const int sd = (t & 3) * 16;

    const bf16* ks0 = Kp + (size_t)(kh0 * 64 + sj) * HDIM + sd;
    const bf16* vs0 = Vp + (size_t)(kh0 * 64 + sj) * HDIM + sd;
    bf16x8 gk0 = *(const bf16x8*)ks0, gk1 = *(const bf16x8*)(ks0 + 8);
    bf16x8 gv0 = *(const bf16x8*)vs0, gv1 = *(const bf16x8*)(vs0 + 8);

    char* pb8 = (char*)pls[wv];
    const int wq0 = wv * 16 + lg * 4;
    int cur = 0;

    for (int kh = kh0; kh <= kh1; ++kh) {
        char* kb8 = (char*)Ks[cur];
        char* vb8 = (char*)vT[cur];
        {
            int kbo = sj * 128 + sd * 2;
            *(bf16x8*)(kb8 + SWZ(sj, kbo)) = gk0;
            *(bf16x8*)(kb8 + SWZ(sj, kbo + 16)) = gk1;
        }
#pragma unroll
        for (int ii = 0; ii < 8; ++ii) {
            int d = sd + ii;
            *(bf16*)(vb8 + SWZ(d, (d << 7) + (sj << 1))) = gv0[ii];
        }
#pragma unroll
        for (int ii = 0; ii < 8; ++ii) {
            int d = sd + 8 + ii;
            *(bf16*)(vb8 + SWZ(d, (d << 7) + (sj << 1))) = gv1[ii];
        }
        if (kh < kh1) {
            const bf16* kn = Kp + (size_t)((kh + 1) * 64 + sj) * HDIM + sd;
            const bf16* vn = Vp + (size_t)((kh + 1) * 64 + sj) * HDIM + sd;
            gk0 = *(const bf16x8*)kn; gk1 = *(const bf16x8*)(kn + 8);
            gv0 = *(const bf16x8*)vn; gv1 = *(const bf16x8*)(vn + 8);
        }
        asm volatile("s_waitcnt lgkmcnt(0)" ::: "memory");
        __builtin_amdgcn_s_barrier();

        // ---- QK^T + P = exp2(s) (static max), accumulate row sums, write P ----
        float psum[4] = {0.f, 0.f, 0.f, 0.f};
#pragma unroll
        for (int jj = 0; jj < 3; ++jj) {
            int j = wv - 1 + jj;
            if (j >= 0 && j <= 3) {        // wave-uniform
                int key = j * 16 + lr;
                int kbase = key * 128;
                bf16x8 kf0 = *(const bf16x8*)(kb8 + SWZ(key, kbase + lg * 16));
                bf16x8 kf1 = *(const bf16x8*)(kb8 + SWZ(key, kbase + 64 + lg * 16));
                f32x4 sv = {};
                sv = G_MFMA(qf[0], kf0, sv);
                sv = G_MFMA(qf[1], kf1, sv);
#pragma unroll
                for (int r = 0; r < 4; ++r) {
                    int dw = wq0 + r - key;
                    float p = (dw >= -5 && dw <= 5) ? exp2f(sv[r]) : 0.0f;
                    psum[r] += p;
                    int row = lg * 4 + r;
                    *(bf16*)(pb8 + SWZ(row, row * 128 + key * 2)) = (bf16)p;
                }
            }
        }
#pragma unroll
        for (int r = 0; r < 4; ++r) lrow[r] += psum[r];

        // ---- PV: A = P[16x64], B = V^T ----
        bf16x8 pf0 = *(const bf16x8*)(pb8 + SWZ(lr, lr * 128 + lg * 16));
        bf16x8 pf1 = *(const bf16x8*)(pb8 + SWZ(lr, lr * 128 + 64 + lg * 16));
#pragma unroll
        for (int dt = 0; dt < 4; ++dt) {
            int vrow = dt * 16 + lr;
            bf16x8 vf0 = *(const bf16x8*)(vb8 + SWZ(vrow, vrow * 128 + lg * 16));
            bf16x8 vf1 = *(const bf16x8*)(vb8 + SWZ(vrow, vrow * 128 + 64 + lg * 16));
            acc[dt] = G_MFMA(pf0, vf0, acc[dt]);
            acc[dt] = G_MFMA(pf1, vf1, acc[dt]);
        }
        cur ^= 1;
    } // kh

    // ---- finalize ----
#pragma unroll
    for (int off = 1; off < 16; off <<= 1)
#pragma unroll
        for (int r = 0; r < 4; ++r) lrow[r] += __shfl_xor(lrow[r], off);

#pragma unroll
    for (int r = 0; r < 4; ++r) {
        float inv = 1.0f / lrow[r];
        int tok = qblk * 64 + wv * 16 + lg * 4 + r;
        size_t rowbase = ((size_t)bidx * NTOK + tok) * KDIM + head * HDIM;
#pragma unroll
        for (int dt = 0; dt < 4; ++dt)
            ob[rowbase + dt * 16 + lr] = (bf16)(acc[dt][r] * inv);
    }
}

// ---------------- launcher ----------------
extern "C" void kernel_launch(void* const* d_in, const int* in_sizes, int n_in,
                              void* d_out, int out_size, void* d_ws, size_t ws_size,
                              hipStream_t stream) {
    const float* x      = (const float*)d_in[0];
    const float* w_qkv  = (const float*)d_in[1];
    const float* w_proj = (const float*)d_in[2];
    const float* b_proj = (const float*)d_in[3];
    float* out = (float*)d_out;

    char* ws = (char*)d_ws;
    bf16* xb  = (bf16*)(ws);                  // 8192*768*2   = 12582912
    bf16* wqb = (bf16*)(ws + 12582912);       // 2304*768*2   =  3538944
    bf16* wpb = (bf16*)(ws + 16121856);       // 768*768*2    =  1179648
    bf16* qb  = (bf16*)(ws + 17301504);       // 96*1024*64*2 = 12582912
    bf16* kb  = (bf16*)(ws + 29884416);
    bf16* vb  = (bf16*)(ws + 42467328);
    bf16* aob = (bf16*)(ws + 55050240);       // attn out bf16 [8192][768]

    hipLaunchKernelGGL(k_cvt_all, dim3(8448), dim3(256), 0, stream, x, w_qkv, w_proj, xb, wqb, wpb);
    hipLaunchKernelGGL(k_gemm_qkv, dim3(64, 12), dim3(256), 0, stream, xb, wqb, qb, kb, vb);
    hipLaunchKernelGGL(k_attn,     dim3(1536), dim3(256), 0, stream, qb, kb, vb, aob);
    hipLaunchKernelGGL(k_gemm_proj, dim3(64, 4), dim3(256), 0, stream, aob, wpb, b_proj, out);
}